// Round 1
// baseline (1803.860 us; speedup 1.0000x reference)
//
#include <hip/hip_runtime.h>
#include <math.h>

// Problem constants (structure fixed by setup_inputs; N/E/G derived from in_sizes)
#define DIN 32
#define DL 128
#define DOUT 10

__device__ __forceinline__ float sigm(float x){ return 1.0f/(1.0f+expf(-x)); }
__device__ __forceinline__ float softplus_(float x){ return fmaxf(x,0.0f) + log1pf(expf(-fabsf(x))); }

// ---------------- graph preprocessing ----------------
__global__ void count_edges_k(const int* __restrict__ ei, int* __restrict__ cnt, int E){
    int e = blockIdx.x*256 + threadIdx.x;
    if (e < E) atomicAdd(&cnt[ei[E + e]], 1);   // dst = ei[1][e]
}

__global__ void dinv_k(const int* __restrict__ cnt, float* __restrict__ dinv, int N){
    int i = blockIdx.x*256 + threadIdx.x;
    if (i < N) dinv[i] = rsqrtf((float)cnt[i] + 1.0f);
}

// single-block scan: rowptr[i+1] = incl sum, cursor[i] = excl sum
__global__ void scan_k(const int* __restrict__ cnt, int* __restrict__ rowptr,
                       int* __restrict__ cursor, int n){
    __shared__ int tmp[1024];
    int tid = threadIdx.x;
    if (tid == 0) rowptr[0] = 0;
    int carry = 0;
    for (int base = 0; base < n; base += 1024){
        int i = base + tid;
        int v = (i < n) ? cnt[i] : 0;
        tmp[tid] = v; __syncthreads();
        for (int off = 1; off < 1024; off <<= 1){
            int t = (tid >= off) ? tmp[tid - off] : 0;
            __syncthreads();
            tmp[tid] += t;
            __syncthreads();
        }
        int incl = tmp[tid];
        if (i < n){ cursor[i] = carry + incl - v; rowptr[i+1] = carry + incl; }
        carry += tmp[1023];
        __syncthreads();
    }
}

__global__ void place_edges_k(const int* __restrict__ ei, int* __restrict__ cursor,
                              int* __restrict__ csr_src, float* __restrict__ csr_w,
                              const float* __restrict__ dinv, int E){
    int e = blockIdx.x*256 + threadIdx.x;
    if (e < E){
        int s = ei[e], d = ei[E + e];
        int pos = atomicAdd(&cursor[d], 1);
        csr_src[pos] = s;
        csr_w[pos] = dinv[s] * dinv[d];
    }
}

// ---------------- input layer: h = sigmoid(x @ W_in + b_in) ----------------
__global__ __launch_bounds__(256) void input_layer_k(const float* __restrict__ x,
        const float* __restrict__ Win, const float* __restrict__ bin,
        float* __restrict__ h, int N){
    __shared__ float Wl[DIN*DL];   // 16 KB
    __shared__ float bl[DL];
    __shared__ float xl[2][DIN];
    int tid = threadIdx.x;
    for (int idx = tid; idx < DIN*DL; idx += 256) Wl[idx] = Win[idx];
    if (tid < DL) bl[tid] = bin[tid];
    int node0 = blockIdx.x*2;
    if (tid < 2*DIN){
        int r = tid >> 5, c = tid & 31;
        int node = node0 + r;
        xl[r][c] = (node < N) ? x[(size_t)node*DIN + c] : 0.0f;
    }
    __syncthreads();
    int node = node0 + (tid >> 7);
    int f = tid & 127;
    if (node < N){
        float acc = bl[f];
        #pragma unroll
        for (int k = 0; k < DIN; ++k) acc += xl[tid>>7][k] * Wl[k*DL + f];
        h[(size_t)node*DL + f] = sigm(acc);
    }
}

// ---------------- generic tiled dense: Out = act(A[nrows,K] @ W[K,ldw] + bias) ----------------
// ACT: 0 none, 1 sigmoid, 2 relu, 3 softplus(x-5)
template<int COLS, int KT, int ACT>
__global__ __launch_bounds__(256) void dense_tiled(const float* __restrict__ A,
        const float* __restrict__ W, const float* __restrict__ bias,
        float* __restrict__ Out, int nrows, int K, int ldw){
    constexpr int BC = COLS/4;
    constexpr int BR = 256/BC;
    constexpr int ROWS = BR*4;
    __shared__ float Al[ROWS][KT+4];
    __shared__ float Wl[KT][COLS];
    int tid = threadIdx.x;
    int tc = tid % BC, tr = tid / BC;
    int row0 = blockIdx.x * ROWS;
    int col0 = blockIdx.y * COLS;
    float acc[4][4] = {{0.f}};
    for (int k0 = 0; k0 < K; k0 += KT){
        for (int idx = tid; idx < ROWS*KT/4; idx += 256){
            int r = idx / (KT/4), kq = idx % (KT/4);
            float4 v = make_float4(0.f,0.f,0.f,0.f);
            if (row0 + r < nrows) v = *(const float4*)&A[(size_t)(row0+r)*K + k0 + kq*4];
            *(float4*)&Al[r][kq*4] = v;
        }
        for (int idx = tid; idx < KT*COLS/4; idx += 256){
            int k = idx / (COLS/4), cq = idx % (COLS/4);
            *(float4*)&Wl[k][cq*4] = *(const float4*)&W[(size_t)(k0+k)*ldw + col0 + cq*4];
        }
        __syncthreads();
        #pragma unroll 4
        for (int k = 0; k < KT; ++k){
            float4 b = *(float4*)&Wl[k][tc*4];
            float a0 = Al[tr*4+0][k], a1 = Al[tr*4+1][k], a2 = Al[tr*4+2][k], a3 = Al[tr*4+3][k];
            acc[0][0] += a0*b.x; acc[0][1] += a0*b.y; acc[0][2] += a0*b.z; acc[0][3] += a0*b.w;
            acc[1][0] += a1*b.x; acc[1][1] += a1*b.y; acc[1][2] += a1*b.z; acc[1][3] += a1*b.w;
            acc[2][0] += a2*b.x; acc[2][1] += a2*b.y; acc[2][2] += a2*b.z; acc[2][3] += a2*b.w;
            acc[3][0] += a3*b.x; acc[3][1] += a3*b.y; acc[3][2] += a3*b.z; acc[3][3] += a3*b.w;
        }
        __syncthreads();
    }
    float bv[4] = {0.f,0.f,0.f,0.f};
    if (bias){
        #pragma unroll
        for (int j = 0; j < 4; ++j) bv[j] = bias[col0 + tc*4 + j];
    }
    #pragma unroll
    for (int i = 0; i < 4; ++i){
        int row = row0 + tr*4 + i;
        if (row < nrows){
            float o[4];
            #pragma unroll
            for (int j = 0; j < 4; ++j){
                float v = acc[i][j] + bv[j];
                if (ACT == 1) v = sigm(v);
                else if (ACT == 2) v = fmaxf(v, 0.0f);
                else if (ACT == 3) v = softplus_(v - 5.0f);
                o[j] = v;
            }
            *(float4*)&Out[(size_t)row*ldw + col0 + tc*4] = *(float4*)o;
        }
    }
}

// ---------------- GCN aggregation: out = sum_{e:dst=n} g[src]*w + g[n]*snorm + b ----------------
__global__ __launch_bounds__(256) void gcn_agg_k(const float4* __restrict__ g4,
        float4* __restrict__ out4, const int* __restrict__ rowptr,
        const int* __restrict__ csr_src, const float* __restrict__ csr_w,
        const float* __restrict__ dinv, const float* __restrict__ bgcn, int N){
    int t = threadIdx.x;
    int node = blockIdx.x*8 + (t >> 5);
    int f4 = t & 31;
    if (node >= N) return;
    float dv = dinv[node];
    float sn = dv*dv;
    float4 acc = g4[(size_t)node*32 + f4];
    float4 b = ((const float4*)bgcn)[f4];
    acc.x = acc.x*sn + b.x; acc.y = acc.y*sn + b.y;
    acc.z = acc.z*sn + b.z; acc.w = acc.w*sn + b.w;
    int e0 = rowptr[node], e1 = rowptr[node+1];
    for (int e = e0; e < e1; ++e){
        int s = csr_src[e];
        float w = csr_w[e];
        float4 gv = g4[(size_t)s*32 + f4];
        acc.x += gv.x*w; acc.y += gv.y*w; acc.z += gv.z*w; acc.w += gv.w*w;
    }
    out4[(size_t)node*32 + f4] = acc;
}

// ---------------- reparametrization: h = mu + std*eps ----------------
__global__ void reparam_k(const float4* __restrict__ mu, const float4* __restrict__ sd,
                          const float4* __restrict__ eps, float4* __restrict__ h, int n4){
    int i = blockIdx.x*256 + threadIdx.x;
    if (i < n4){
        float4 m = mu[i], s = sd[i], e = eps[i], o;
        o.x = m.x + s.x*e.x; o.y = m.y + s.y*e.y; o.z = m.z + s.z*e.z; o.w = m.w + s.w*e.w;
        h[i] = o;
    }
}

// ---------------- final layer (16->10, sigmoid) fused with mean-pool accumulation ----------------
__global__ __launch_bounds__(256) void final_pool_k(const float* __restrict__ d16,
        const float* __restrict__ Wo, const float* __restrict__ bo,
        const int* __restrict__ batch, float* __restrict__ sums,
        float* __restrict__ gcnt, int N){
    __shared__ float WoL[16*DOUT];
    __shared__ float boL[DOUT];
    int tid = threadIdx.x;
    if (tid < 16*DOUT) WoL[tid] = Wo[tid];
    if (tid < DOUT) boL[tid] = bo[tid];
    __syncthreads();
    int node = blockIdx.x*256 + tid;
    float yp[DOUT];
    int b = -1;
    if (node < N){
        const float4* d4 = (const float4*)d16;
        float dd[16];
        #pragma unroll
        for (int q = 0; q < 4; ++q){
            float4 v = d4[(size_t)node*4 + q];
            dd[q*4+0]=v.x; dd[q*4+1]=v.y; dd[q*4+2]=v.z; dd[q*4+3]=v.w;
        }
        #pragma unroll
        for (int o = 0; o < DOUT; ++o){
            float acc = boL[o];
            #pragma unroll
            for (int k = 0; k < 16; ++k) acc += dd[k]*WoL[k*DOUT+o];
            yp[o] = sigm(acc);
        }
        b = batch[node];
    }
    int b0 = __builtin_amdgcn_readfirstlane(b);
    unsigned long long m = __ballot(b == b0);
    if (m == ~0ull && b0 >= 0){
        // wave-uniform graph: reduce across 64 lanes, single atomic per wave
        #pragma unroll
        for (int o = 0; o < DOUT; ++o){
            float v = yp[o];
            for (int off = 32; off > 0; off >>= 1) v += __shfl_xor(v, off);
            if ((tid & 63) == 0) atomicAdd(&sums[b0*DOUT + o], v);
        }
        if ((tid & 63) == 0) atomicAdd(&gcnt[b0], 64.0f);
    } else if (node < N){
        #pragma unroll
        for (int o = 0; o < DOUT; ++o) atomicAdd(&sums[b*DOUT + o], yp[o]);
        atomicAdd(&gcnt[b], 1.0f);
    }
}

__global__ void divide_k(float* __restrict__ out, const float* __restrict__ gcnt, int n){
    int i = blockIdx.x*256 + threadIdx.x;
    if (i < n) out[i] = out[i] / fmaxf(gcnt[i/DOUT], 1.0f);
}

__global__ void copy_k(const float* __restrict__ src, float* __restrict__ dst, int n){
    int i = blockIdx.x*256 + threadIdx.x;
    if (i < n) dst[i] = src[i];
}

extern "C" void kernel_launch(void* const* d_in, const int* in_sizes, int n_in,
                              void* d_out, int out_size, void* d_ws, size_t ws_size,
                              hipStream_t stream) {
    const float* x     = (const float*)d_in[0];
    const int*   ei    = (const int*)d_in[1];
    const int*   batch = (const int*)d_in[2];
    const float* y     = (const float*)d_in[3];
    const float* eps   = (const float*)d_in[4];
    const float* W_in  = (const float*)d_in[5];
    const float* b_in  = (const float*)d_in[6];
    const float* W_gcn = (const float*)d_in[7];
    const float* b_gcn = (const float*)d_in[8];
    const float* W_enc = (const float*)d_in[9];
    const float* b_enc = (const float*)d_in[10];
    const float* W_mu  = (const float*)d_in[11];
    const float* b_mu  = (const float*)d_in[12];
    const float* W_std = (const float*)d_in[13];
    const float* b_std = (const float*)d_in[14];
    const float* Wd0 = (const float*)d_in[15]; const float* bd0 = (const float*)d_in[16];
    const float* Wd1 = (const float*)d_in[17]; const float* bd1 = (const float*)d_in[18];
    const float* Wd2 = (const float*)d_in[19]; const float* bd2 = (const float*)d_in[20];
    const float* Wd3 = (const float*)d_in[21]; const float* bd3 = (const float*)d_in[22];
    const float* Wd4 = (const float*)d_in[23]; const float* bd4 = (const float*)d_in[24];
    const float* Wo  = (const float*)d_in[25]; const float* bo  = (const float*)d_in[26];

    const int N = in_sizes[2];
    const int E = in_sizes[1]/2;
    const int G = in_sizes[3]/DOUT;
    const int KHOP = in_sizes[4] / (N*DL);   // = 3

    // workspace layout
    float* F = (float*)d_ws;
    size_t NN = (size_t)N*DL;
    float* bufH  = F;
    float* bufG  = F + NN;
    float* bufG2 = F + 2*NN;
    float* bufMu = F + 3*NN;     // bufMu..bufStd also serve as decoder A buffer [N,256]
    float* bufSd = F + 4*NN;
    float* csr_w = F + 5*NN;
    float* dinv  = csr_w + E;
    float* gcnt  = dinv + N;
    int* cnt     = (int*)(gcnt + G);
    int* rowptr  = cnt + N;
    int* cursor  = rowptr + N + 1;
    int* csr_src = cursor + N;
    float* bufA  = bufMu;        // [N,256]

    float* out_ypred = (float*)d_out;                    // [G,10]
    float* out_mu    = out_ypred + (size_t)G*DOUT;       // [N,128]
    float* out_std   = out_mu + NN;                      // [N,128]
    float* out_y     = out_std + NN;                     // [G,10]

    // zero accumulators (ws/d_out are poisoned before each call)
    hipMemsetAsync(cnt, 0, sizeof(int)*N, stream);
    hipMemsetAsync(out_ypred, 0, sizeof(float)*G*DOUT, stream);
    hipMemsetAsync(gcnt, 0, sizeof(float)*G, stream);

    int gE = (E + 255)/256, gN = (N + 255)/256;

    // graph preprocessing: degree -> dinv -> CSR by dst
    count_edges_k<<<gE, 256, 0, stream>>>(ei, cnt, E);
    dinv_k<<<gN, 256, 0, stream>>>(cnt, dinv, N);
    scan_k<<<1, 1024, 0, stream>>>(cnt, rowptr, cursor, N);
    place_edges_k<<<gE, 256, 0, stream>>>(ei, cursor, csr_src, csr_w, dinv, E);

    // input layer
    input_layer_k<<<(N+1)/2, 256, 0, stream>>>(x, W_in, b_in, bufH, N);

    dim3 g128((N + 31)/32, 1);      // COLS=128, ROWS=32
    // K hops
    for (int i = 0; i < KHOP; ++i){
        bool last = (i == KHOP-1);
        float* muP = last ? out_mu : bufMu;
        float* sdP = last ? out_std : bufSd;
        // g = h @ W_gcn (no bias)
        dense_tiled<128,64,0><<<g128, 256, 0, stream>>>(bufH, W_gcn, nullptr, bufG, N, DL, DL);
        // aggregate
        gcn_agg_k<<<(N+7)/8, 256, 0, stream>>>((const float4*)bufG, (float4*)bufG2,
                                               rowptr, csr_src, csr_w, dinv, b_gcn, N);
        // 5 encoder layers (sigmoid), ping-pong G2 <-> G, end in bufG
        const float* src = bufG2; float* dst = bufG;
        for (int j = 0; j < 5; ++j){
            dense_tiled<128,64,1><<<g128, 256, 0, stream>>>(src, W_enc + (size_t)j*DL*DL,
                                                            b_enc + j*DL, dst, N, DL, DL);
            const float* tmp = dst; dst = (float*)src; src = tmp;
        }
        const float* gfin = src;  // after odd number of swaps: bufG
        // mu / std
        dense_tiled<128,64,0><<<g128, 256, 0, stream>>>(gfin, W_mu, b_mu, muP, N, DL, DL);
        dense_tiled<128,64,3><<<g128, 256, 0, stream>>>(gfin, W_std, b_std, sdP, N, DL, DL);
        // h = mu + std*eps[i]
        int n4 = (int)(NN/4);
        reparam_k<<<(n4+255)/256, 256, 0, stream>>>((const float4*)muP, (const float4*)sdP,
                                                    (const float4*)(eps + (size_t)i*NN),
                                                    (float4*)bufH, n4);
    }

    // decoder MLP
    dim3 gL0((N + 31)/32, 2);
    dense_tiled<128,64,2><<<gL0, 256, 0, stream>>>(bufH, Wd0, bd0, bufA, N, 128, 256);
    dense_tiled<128,64,2><<<g128, 256, 0, stream>>>(bufA, Wd1, bd1, bufG, N, 256, 128);
    dense_tiled<64,64,2><<<dim3((N+63)/64,1), 256, 0, stream>>>(bufG, Wd2, bd2, bufG2, N, 128, 64);
    dense_tiled<32,64,2><<<dim3((N+127)/128,1), 256, 0, stream>>>(bufG2, Wd3, bd3, bufG, N, 64, 32);
    dense_tiled<16,32,2><<<dim3((N+255)/256,1), 256, 0, stream>>>(bufG, Wd4, bd4, bufG2, N, 32, 16);

    // final layer + pooling
    final_pool_k<<<(N+255)/256, 256, 0, stream>>>(bufG2, Wo, bo, batch, out_ypred, gcnt, N);
    divide_k<<<(G*DOUT+255)/256, 256, 0, stream>>>(out_ypred, gcnt, G*DOUT);
    copy_k<<<(G*DOUT+255)/256, 256, 0, stream>>>(y, out_y, G*DOUT);
}

// Round 2
// 1197.371 us; speedup vs baseline: 1.5065x; 1.5065x over previous
//
#include <hip/hip_runtime.h>
#include <math.h>

#define DIN 32
#define DL 128
#define DOUT 10

typedef _Float16 f16x8 __attribute__((ext_vector_type(8)));
typedef _Float16 f16x4 __attribute__((ext_vector_type(4)));
typedef float f32x4 __attribute__((ext_vector_type(4)));

__device__ __forceinline__ float sigm(float x){ return 1.0f/(1.0f+expf(-x)); }
__device__ __forceinline__ float softplus_(float x){ return fmaxf(x,0.0f) + log1pf(expf(-fabsf(x))); }

// ---------------- graph preprocessing ----------------
__global__ void count_edges_k(const int* __restrict__ ei, int* __restrict__ cnt, int E){
    int e = blockIdx.x*256 + threadIdx.x;
    if (e < E) atomicAdd(&cnt[ei[E + e]], 1);   // dst = ei[1][e]
}

__global__ void dinv_k(const int* __restrict__ cnt, float* __restrict__ dinv, int N){
    int i = blockIdx.x*256 + threadIdx.x;
    if (i < N) dinv[i] = rsqrtf((float)cnt[i] + 1.0f);
}

// hierarchical scan: (1) per-block sums, (2) scan of block sums, (3) rescan w/ offset
__global__ void block_sum_k(const int* __restrict__ cnt, int* __restrict__ bsum, int n){
    __shared__ int ws_[4];
    int tid = threadIdx.x;
    int i = blockIdx.x*256 + tid;
    int v = (i < n) ? cnt[i] : 0;
    #pragma unroll
    for (int off = 32; off > 0; off >>= 1) v += __shfl_xor(v, off);
    if ((tid & 63) == 0) ws_[tid >> 6] = v;
    __syncthreads();
    if (tid == 0) bsum[blockIdx.x] = ws_[0] + ws_[1] + ws_[2] + ws_[3];
}

__global__ void scan_bsum_k(int* __restrict__ bsum, int nb){
    __shared__ int tmp[1024];
    int tid = threadIdx.x;
    int v = (tid < nb) ? bsum[tid] : 0;
    tmp[tid] = v; __syncthreads();
    for (int off = 1; off < 1024; off <<= 1){
        int t = (tid >= off) ? tmp[tid-off] : 0;
        __syncthreads();
        tmp[tid] += t;
        __syncthreads();
    }
    if (tid < nb) bsum[tid] = tmp[tid] - v;   // exclusive
}

__global__ void block_scan_k(const int* __restrict__ cnt, const int* __restrict__ bexcl,
                             int* __restrict__ cursor, int* __restrict__ rowptr, int n){
    __shared__ int tmp[256];
    int tid = threadIdx.x;
    int i = blockIdx.x*256 + tid;
    int v = (i < n) ? cnt[i] : 0;
    tmp[tid] = v; __syncthreads();
    for (int off = 1; off < 256; off <<= 1){
        int t = (tid >= off) ? tmp[tid-off] : 0;
        __syncthreads();
        tmp[tid] += t;
        __syncthreads();
    }
    int excl = bexcl[blockIdx.x] + tmp[tid] - v;
    if (i < n){ cursor[i] = excl; rowptr[i+1] = excl + v; }
    if (i == 0) rowptr[0] = 0;
}

__global__ void place_edges_k(const int* __restrict__ ei, int* __restrict__ cursor,
                              int* __restrict__ csr_src, float* __restrict__ csr_w,
                              const float* __restrict__ dinv, int E){
    int e = blockIdx.x*256 + threadIdx.x;
    if (e < E){
        int s = ei[e], d = ei[E + e];
        int pos = atomicAdd(&cursor[d], 1);
        csr_src[pos] = s;
        csr_w[pos] = dinv[s] * dinv[d];
    }
}

// ---------------- weight prep: fp32 [K][C] -> fp16 transposed [C][K] ----------------
__global__ void wprep7_k(const float* __restrict__ Wgcn, const float* __restrict__ Wenc,
                         const float* __restrict__ Wmu, const float* __restrict__ Wstd,
                         _Float16* __restrict__ dst){
    int m = blockIdx.y;   // 0:gcn 1-5:enc 6:mu 7:std
    const float* src = (m == 0) ? Wgcn : (m <= 5 ? Wenc + (size_t)(m-1)*DL*DL : (m == 6 ? Wmu : Wstd));
    _Float16* d = dst + (size_t)m*DL*DL;
    int idx = blockIdx.x*256 + threadIdx.x;     // 64 blocks x -> 16384
    int k = idx >> 7, c = idx & 127;
    d[(size_t)c*DL + k] = (_Float16)src[idx];
}

__global__ void wprep_t_k(const float* __restrict__ src, _Float16* __restrict__ dst, int K, int C){
    int idx = blockIdx.x*256 + threadIdx.x;
    if (idx < K*C){ int k = idx / C, c = idx % C; dst[(size_t)c*K + k] = (_Float16)src[idx]; }
}

// ---------------- input layer: h = sigmoid(x @ W_in + b_in), fp16 out ----------------
__global__ __launch_bounds__(256) void input_layer_k(const float* __restrict__ x,
        const float* __restrict__ Win, const float* __restrict__ bin,
        _Float16* __restrict__ h, int N){
    __shared__ float Wl[DIN*DL];
    __shared__ float bl[DL];
    __shared__ float xl[2][DIN];
    int tid = threadIdx.x;
    for (int idx = tid; idx < DIN*DL; idx += 256) Wl[idx] = Win[idx];
    if (tid < DL) bl[tid] = bin[tid];
    int node0 = blockIdx.x*2;
    if (tid < 2*DIN){
        int r = tid >> 5, c = tid & 31;
        int node = node0 + r;
        xl[r][c] = (node < N) ? x[(size_t)node*DIN + c] : 0.0f;
    }
    __syncthreads();
    int node = node0 + (tid >> 7);
    int f = tid & 127;
    if (node < N){
        float acc = bl[f];
        #pragma unroll
        for (int k = 0; k < DIN; ++k) acc += xl[tid>>7][k] * Wl[k*DL + f];
        h[(size_t)node*DL + f] = (_Float16)sigm(acc);
    }
}

// ---------------- fp16 MFMA GEMM: Out = act(A[nrows,K] @ W + bias), 128-col block ----------------
// A fp16 row-major [nrows,K]; Wt fp16 TRANSPOSED [ncols][K]; bias fp32 or null.
// ACT: 0 none, 1 sigmoid, 2 relu, 3 softplus(x-5).  F16OUT: 1 -> fp16 store, 0 -> fp32.
template<int ACT, int F16OUT>
__global__ __launch_bounds__(256) void mfma_gemm(const _Float16* __restrict__ A,
        const _Float16* __restrict__ Wt, const float* __restrict__ bias,
        void* __restrict__ OutV, int nrows, int K, int ldo){
    __shared__ __align__(16) _Float16 Al[128][72];   // KT=64, +8 pad
    __shared__ __align__(16) _Float16 Wl[128][72];
    int tid = threadIdx.x;
    int lane = tid & 63, wid = tid >> 6;
    int ln = lane & 15, q = lane >> 4;
    int row0 = blockIdx.x * 128;
    int col0 = blockIdx.y * 128;
    f32x4 acc[2][8];
    #pragma unroll
    for (int r = 0; r < 2; ++r)
        #pragma unroll
        for (int c = 0; c < 8; ++c) acc[r][c] = (f32x4){0.f,0.f,0.f,0.f};

    for (int k0 = 0; k0 < K; k0 += 64){
        // stage A-tile and Wt-tile: 128 rows x 64 halves each, 16B granules
        for (int g = tid; g < 1024; g += 256){
            int r = g >> 3, s = g & 7;
            f16x8 v = {};
            int gr = row0 + r;
            if (gr < nrows) v = *(const f16x8*)&A[(size_t)gr*K + k0 + s*8];
            *(f16x8*)&Al[r][s*8] = v;
            *(f16x8*)&Wl[r][s*8] = *(const f16x8*)&Wt[(size_t)(col0 + r)*K + k0 + s*8];
        }
        __syncthreads();
        #pragma unroll
        for (int kk = 0; kk < 2; ++kk){
            int ko = kk*32 + q*8;
            f16x8 a0 = *(const f16x8*)&Al[wid*32 + ln][ko];
            f16x8 a1 = *(const f16x8*)&Al[wid*32 + 16 + ln][ko];
            #pragma unroll
            for (int c = 0; c < 8; ++c){
                f16x8 b = *(const f16x8*)&Wl[c*16 + ln][ko];
                acc[0][c] = __builtin_amdgcn_mfma_f32_16x16x32_f16(a0, b, acc[0][c], 0, 0, 0);
                acc[1][c] = __builtin_amdgcn_mfma_f32_16x16x32_f16(a1, b, acc[1][c], 0, 0, 0);
            }
        }
        __syncthreads();
    }
    // epilogue: C/D layout col=lane&15, row=(lane>>4)*4+reg
    #pragma unroll
    for (int r = 0; r < 2; ++r){
        int rowb = row0 + wid*32 + r*16 + q*4;
        #pragma unroll
        for (int c = 0; c < 8; ++c){
            int col = col0 + c*16 + ln;
            float bv = bias ? bias[col] : 0.0f;
            #pragma unroll
            for (int i2 = 0; i2 < 4; ++i2){
                int row = rowb + i2;
                if (row < nrows){
                    float v = acc[r][c][i2] + bv;
                    if (ACT == 1) v = sigm(v);
                    else if (ACT == 2) v = fmaxf(v, 0.0f);
                    else if (ACT == 3) v = softplus_(v - 5.0f);
                    if (F16OUT) ((_Float16*)OutV)[(size_t)row*ldo + col] = (_Float16)v;
                    else        ((float*)OutV)[(size_t)row*ldo + col] = v;
                }
            }
        }
    }
}

// ---------------- fp32 tiled dense (kept for small decoder layers) ----------------
template<int COLS, int KT, int ACT>
__global__ __launch_bounds__(256) void dense_tiled(const float* __restrict__ A,
        const float* __restrict__ W, const float* __restrict__ bias,
        float* __restrict__ Out, int nrows, int K, int ldw){
    constexpr int BC = COLS/4;
    constexpr int BR = 256/BC;
    constexpr int ROWS = BR*4;
    __shared__ float Al[ROWS][KT+4];
    __shared__ float Wl[KT][COLS];
    int tid = threadIdx.x;
    int tc = tid % BC, tr = tid / BC;
    int row0 = blockIdx.x * ROWS;
    int col0 = blockIdx.y * COLS;
    float acc[4][4] = {{0.f}};
    for (int k0 = 0; k0 < K; k0 += KT){
        for (int idx = tid; idx < ROWS*KT/4; idx += 256){
            int r = idx / (KT/4), kq = idx % (KT/4);
            float4 v = make_float4(0.f,0.f,0.f,0.f);
            if (row0 + r < nrows) v = *(const float4*)&A[(size_t)(row0+r)*K + k0 + kq*4];
            *(float4*)&Al[r][kq*4] = v;
        }
        for (int idx = tid; idx < KT*COLS/4; idx += 256){
            int k = idx / (COLS/4), cq = idx % (COLS/4);
            *(float4*)&Wl[k][cq*4] = *(const float4*)&W[(size_t)(k0+k)*ldw + col0 + cq*4];
        }
        __syncthreads();
        #pragma unroll 4
        for (int k = 0; k < KT; ++k){
            float4 b = *(float4*)&Wl[k][tc*4];
            float a0 = Al[tr*4+0][k], a1 = Al[tr*4+1][k], a2 = Al[tr*4+2][k], a3 = Al[tr*4+3][k];
            acc[0][0] += a0*b.x; acc[0][1] += a0*b.y; acc[0][2] += a0*b.z; acc[0][3] += a0*b.w;
            acc[1][0] += a1*b.x; acc[1][1] += a1*b.y; acc[1][2] += a1*b.z; acc[1][3] += a1*b.w;
            acc[2][0] += a2*b.x; acc[2][1] += a2*b.y; acc[2][2] += a2*b.z; acc[2][3] += a2*b.w;
            acc[3][0] += a3*b.x; acc[3][1] += a3*b.y; acc[3][2] += a3*b.z; acc[3][3] += a3*b.w;
        }
        __syncthreads();
    }
    float bv[4] = {0.f,0.f,0.f,0.f};
    if (bias){
        #pragma unroll
        for (int j = 0; j < 4; ++j) bv[j] = bias[col0 + tc*4 + j];
    }
    #pragma unroll
    for (int i = 0; i < 4; ++i){
        int row = row0 + tr*4 + i;
        if (row < nrows){
            float o[4];
            #pragma unroll
            for (int j = 0; j < 4; ++j){
                float v = acc[i][j] + bv[j];
                if (ACT == 1) v = sigm(v);
                else if (ACT == 2) v = fmaxf(v, 0.0f);
                else if (ACT == 3) v = softplus_(v - 5.0f);
                o[j] = v;
            }
            *(float4*)&Out[(size_t)row*ldw + col0 + tc*4] = *(float4*)o;
        }
    }
}

// ---------------- GCN aggregation (fp16 in/out, fp32 accum) ----------------
__global__ __launch_bounds__(256) void gcn_agg_h(const _Float16* __restrict__ g,
        _Float16* __restrict__ out, const int* __restrict__ rowptr,
        const int* __restrict__ csr_src, const float* __restrict__ csr_w,
        const float* __restrict__ dinv, const float* __restrict__ bgcn, int N){
    int t = threadIdx.x;
    int node = blockIdx.x*16 + (t >> 4);
    int f = (t & 15)*8;
    if (node >= N) return;
    float dv = dinv[node];
    float sn = dv*dv;
    f16x8 sv = *(const f16x8*)&g[(size_t)node*DL + f];
    float acc[8];
    #pragma unroll
    for (int j = 0; j < 8; ++j) acc[j] = (float)sv[j]*sn + bgcn[f+j];
    int e0 = rowptr[node], e1 = rowptr[node+1];
    for (int e = e0; e < e1; ++e){
        int s = csr_src[e];
        float w = csr_w[e];
        f16x8 nv = *(const f16x8*)&g[(size_t)s*DL + f];
        #pragma unroll
        for (int j = 0; j < 8; ++j) acc[j] += (float)nv[j]*w;
    }
    f16x8 o;
    #pragma unroll
    for (int j = 0; j < 8; ++j) o[j] = (_Float16)acc[j];
    *(f16x8*)&out[(size_t)node*DL + f] = o;
}

// ---------------- reparametrization: h = mu + std*eps (fp32 in, fp16 out) ----------------
__global__ void reparam_h_k(const float4* __restrict__ mu, const float4* __restrict__ sd,
                            const float4* __restrict__ eps, f16x4* __restrict__ h, int n4){
    int i = blockIdx.x*256 + threadIdx.x;
    if (i < n4){
        float4 m = mu[i], s = sd[i], e = eps[i];
        f16x4 o;
        o[0] = (_Float16)(m.x + s.x*e.x);
        o[1] = (_Float16)(m.y + s.y*e.y);
        o[2] = (_Float16)(m.z + s.z*e.z);
        o[3] = (_Float16)(m.w + s.w*e.w);
        h[i] = o;
    }
}

// ---------------- final layer (16->10, sigmoid) fused with mean-pool ----------------
__global__ __launch_bounds__(256) void final_pool_k(const float* __restrict__ d16,
        const float* __restrict__ Wo, const float* __restrict__ bo,
        const int* __restrict__ batch, float* __restrict__ sums,
        float* __restrict__ gcnt, int N){
    __shared__ float WoL[16*DOUT];
    __shared__ float boL[DOUT];
    int tid = threadIdx.x;
    if (tid < 16*DOUT) WoL[tid] = Wo[tid];
    if (tid < DOUT) boL[tid] = bo[tid];
    __syncthreads();
    int node = blockIdx.x*256 + tid;
    float yp[DOUT];
    int b = -1;
    if (node < N){
        const float4* d4 = (const float4*)d16;
        float dd[16];
        #pragma unroll
        for (int q = 0; q < 4; ++q){
            float4 v = d4[(size_t)node*4 + q];
            dd[q*4+0]=v.x; dd[q*4+1]=v.y; dd[q*4+2]=v.z; dd[q*4+3]=v.w;
        }
        #pragma unroll
        for (int o = 0; o < DOUT; ++o){
            float acc = boL[o];
            #pragma unroll
            for (int k = 0; k < 16; ++k) acc += dd[k]*WoL[k*DOUT+o];
            yp[o] = sigm(acc);
        }
        b = batch[node];
    }
    int b0 = __builtin_amdgcn_readfirstlane(b);
    unsigned long long m = __ballot(b == b0);
    if (m == ~0ull && b0 >= 0){
        #pragma unroll
        for (int o = 0; o < DOUT; ++o){
            float v = yp[o];
            for (int off = 32; off > 0; off >>= 1) v += __shfl_xor(v, off);
            if ((tid & 63) == 0) atomicAdd(&sums[b0*DOUT + o], v);
        }
        if ((tid & 63) == 0) atomicAdd(&gcnt[b0], 64.0f);
    } else if (node < N){
        #pragma unroll
        for (int o = 0; o < DOUT; ++o) atomicAdd(&sums[b*DOUT + o], yp[o]);
        atomicAdd(&gcnt[b], 1.0f);
    }
}

__global__ void divide_k(float* __restrict__ out, const float* __restrict__ gcnt, int n){
    int i = blockIdx.x*256 + threadIdx.x;
    if (i < n) out[i] = out[i] / fmaxf(gcnt[i/DOUT], 1.0f);
}

__global__ void copy_k(const float* __restrict__ src, float* __restrict__ dst, int n){
    int i = blockIdx.x*256 + threadIdx.x;
    if (i < n) dst[i] = src[i];
}

extern "C" void kernel_launch(void* const* d_in, const int* in_sizes, int n_in,
                              void* d_out, int out_size, void* d_ws, size_t ws_size,
                              hipStream_t stream) {
    const float* x     = (const float*)d_in[0];
    const int*   ei    = (const int*)d_in[1];
    const int*   batch = (const int*)d_in[2];
    const float* y     = (const float*)d_in[3];
    const float* eps   = (const float*)d_in[4];
    const float* W_in  = (const float*)d_in[5];
    const float* b_in  = (const float*)d_in[6];
    const float* W_gcn = (const float*)d_in[7];
    const float* b_gcn = (const float*)d_in[8];
    const float* W_enc = (const float*)d_in[9];
    const float* b_enc = (const float*)d_in[10];
    const float* W_mu  = (const float*)d_in[11];
    const float* b_mu  = (const float*)d_in[12];
    const float* W_std = (const float*)d_in[13];
    const float* b_std = (const float*)d_in[14];
    const float* Wd0 = (const float*)d_in[15]; const float* bd0 = (const float*)d_in[16];
    const float* Wd1 = (const float*)d_in[17]; const float* bd1 = (const float*)d_in[18];
    const float* Wd2 = (const float*)d_in[19]; const float* bd2 = (const float*)d_in[20];
    const float* Wd3 = (const float*)d_in[21]; const float* bd3 = (const float*)d_in[22];
    const float* Wd4 = (const float*)d_in[23]; const float* bd4 = (const float*)d_in[24];
    const float* Wo  = (const float*)d_in[25]; const float* bo  = (const float*)d_in[26];

    const int N = in_sizes[2];
    const int E = in_sizes[1]/2;
    const int G = in_sizes[3]/DOUT;
    const int KHOP = in_sizes[4] / (N*DL);   // = 3
    const size_t NN = (size_t)N*DL;

    // ---- workspace carve (256B-aligned chunks) ----
    char* p = (char*)d_ws;
    auto take = [&p](size_t bytes) -> char* {
        char* r = p; p += (bytes + 255) & ~(size_t)255; return r;
    };
    _Float16* hH  = (_Float16*)take(NN*2);          // activations fp16 [N,128]
    _Float16* hG  = (_Float16*)take(NN*2);
    _Float16* hG2 = (_Float16*)take(NN*2);
    _Float16* hA  = (_Float16*)take((size_t)N*256*2); // decoder0 out [N,256]
    float* muT  = (float*)take(NN*4);               // fp32 temporaries (reused by decoder)
    float* stdT = (float*)take(NN*4);
    float* csr_w = (float*)take((size_t)E*4);
    float* dinv  = (float*)take((size_t)N*4);
    float* gcnt  = (float*)take((size_t)G*4);
    int* cnt     = (int*)take((size_t)N*4);
    int* rowptr  = (int*)take((size_t)(N+1)*4);
    int* cursor  = (int*)take((size_t)N*4);
    int* csr_src = (int*)take((size_t)E*4);
    int* bsum    = (int*)take(1024*4);
    _Float16* Wt8  = (_Float16*)take((size_t)8*DL*DL*2); // gcn, enc0..4, mu, std (transposed)
    _Float16* WtD0 = (_Float16*)take((size_t)256*128*2);
    _Float16* WtD1 = (_Float16*)take((size_t)128*256*2);
    _Float16* WtGCN = Wt8;
    _Float16* WtENC = Wt8 + (size_t)1*DL*DL;
    _Float16* WtMU  = Wt8 + (size_t)6*DL*DL;
    _Float16* WtSTD = Wt8 + (size_t)7*DL*DL;

    float* out_ypred = (float*)d_out;                    // [G,10]
    float* out_mu    = out_ypred + (size_t)G*DOUT;       // [N,128]
    float* out_std   = out_mu + NN;                      // [N,128]
    float* out_y     = out_std + NN;                     // [G,10]

    hipMemsetAsync(cnt, 0, sizeof(int)*N, stream);
    hipMemsetAsync(out_ypred, 0, sizeof(float)*G*DOUT, stream);
    hipMemsetAsync(gcnt, 0, sizeof(float)*G, stream);

    int gE = (E + 255)/256, gN = (N + 255)/256;
    int nb = gN;  // #scan blocks (196 <= 1024)

    // graph preprocessing
    count_edges_k<<<gE, 256, 0, stream>>>(ei, cnt, E);
    dinv_k<<<gN, 256, 0, stream>>>(cnt, dinv, N);
    block_sum_k<<<nb, 256, 0, stream>>>(cnt, bsum, N);
    scan_bsum_k<<<1, 1024, 0, stream>>>(bsum, nb);
    block_scan_k<<<nb, 256, 0, stream>>>(cnt, bsum, cursor, rowptr, N);
    place_edges_k<<<gE, 256, 0, stream>>>(ei, cursor, csr_src, csr_w, dinv, E);

    // weight prep (fp16, transposed)
    wprep7_k<<<dim3(64, 8), 256, 0, stream>>>(W_gcn, W_enc, W_mu, W_std, Wt8);
    wprep_t_k<<<128, 256, 0, stream>>>(Wd0, WtD0, 128, 256);
    wprep_t_k<<<128, 256, 0, stream>>>(Wd1, WtD1, 256, 128);

    // input layer
    input_layer_k<<<(N+1)/2, 256, 0, stream>>>(x, W_in, b_in, hH, N);

    dim3 gemm128((N + 127)/128, 1);
    int n4 = (int)(NN/4);
    for (int i = 0; i < KHOP; ++i){
        bool last = (i == KHOP-1);
        float* muP = last ? out_mu : muT;
        float* sdP = last ? out_std : stdT;
        // g = h @ W_gcn
        mfma_gemm<0,1><<<gemm128, 256, 0, stream>>>(hH, WtGCN, nullptr, hG, N, DL, DL);
        // aggregate
        gcn_agg_h<<<(N+15)/16, 256, 0, stream>>>(hG, hG2, rowptr, csr_src, csr_w, dinv, b_gcn, N);
        // 5 encoder layers (sigmoid), ping-pong hG2 <-> hG, end in hG
        const _Float16* src = hG2; _Float16* dst = hG;
        for (int j = 0; j < 5; ++j){
            mfma_gemm<1,1><<<gemm128, 256, 0, stream>>>(src, WtENC + (size_t)j*DL*DL,
                                                        b_enc + j*DL, dst, N, DL, DL);
            const _Float16* tmp = dst; dst = (_Float16*)src; src = tmp;
        }
        const _Float16* gfin = src;  // hG after 5 swaps
        // mu / std (fp32 out)
        mfma_gemm<0,0><<<gemm128, 256, 0, stream>>>(gfin, WtMU, b_mu, muP, N, DL, DL);
        mfma_gemm<3,0><<<gemm128, 256, 0, stream>>>(gfin, WtSTD, b_std, sdP, N, DL, DL);
        // h = mu + std*eps[i] (fp16 out)
        reparam_h_k<<<(n4+255)/256, 256, 0, stream>>>((const float4*)muP, (const float4*)sdP,
                                                      (const float4*)(eps + (size_t)i*NN),
                                                      (f16x4*)hH, n4);
    }

    // decoder: 128->256 (fp16), 256->128 (fp32 out), then fp32 small layers
    mfma_gemm<2,1><<<dim3((N+127)/128, 2), 256, 0, stream>>>(hH, WtD0, bd0, hA, N, 128, 256);
    mfma_gemm<2,0><<<gemm128, 256, 0, stream>>>(hA, WtD1, bd1, muT, N, 256, DL);
    dense_tiled<64,64,2><<<dim3((N+63)/64,1), 256, 0, stream>>>(muT, Wd2, bd2, stdT, N, 128, 64);
    dense_tiled<32,64,2><<<dim3((N+127)/128,1), 256, 0, stream>>>(stdT, Wd3, bd3, muT, N, 64, 32);
    dense_tiled<16,32,2><<<dim3((N+255)/256,1), 256, 0, stream>>>(muT, Wd4, bd4, stdT, N, 32, 16);

    // final layer + pooling
    final_pool_k<<<(N+255)/256, 256, 0, stream>>>(stdT, Wo, bo, batch, out_ypred, gcnt, N);
    divide_k<<<(G*DOUT+255)/256, 256, 0, stream>>>(out_ypred, gcnt, G*DOUT);
    copy_k<<<(G*DOUT+255)/256, 256, 0, stream>>>(y, out_y, G*DOUT);
}

// Round 3
// 969.814 us; speedup vs baseline: 1.8600x; 1.2346x over previous
//
#include <hip/hip_runtime.h>
#include <math.h>

#define DIN 32
#define DL 128
#define DOUT 10

typedef _Float16 f16x8 __attribute__((ext_vector_type(8)));
typedef float f32x4 __attribute__((ext_vector_type(4)));

__device__ __forceinline__ float sigm(float x){ return 1.0f/(1.0f+expf(-x)); }
__device__ __forceinline__ float softplus_(float x){ return fmaxf(x,0.0f) + log1pf(expf(-fabsf(x))); }

// ================= graph preprocessing =================
__global__ void count_edges_k(const int* __restrict__ ei, int* __restrict__ cnt, int E){
    int e = blockIdx.x*256 + threadIdx.x;
    if (e < E) atomicAdd(&cnt[ei[E + e]], 1);   // dst = ei[1][e]
}

__global__ void dinv_k(const int* __restrict__ cnt, float* __restrict__ dinv, int N){
    int i = blockIdx.x*256 + threadIdx.x;
    if (i < N) dinv[i] = rsqrtf((float)cnt[i] + 1.0f);
}

__global__ void block_sum_k(const int* __restrict__ cnt, int* __restrict__ bsum, int n){
    __shared__ int ws_[4];
    int tid = threadIdx.x;
    int i = blockIdx.x*256 + tid;
    int v = (i < n) ? cnt[i] : 0;
    #pragma unroll
    for (int off = 32; off > 0; off >>= 1) v += __shfl_xor(v, off);
    if ((tid & 63) == 0) ws_[tid >> 6] = v;
    __syncthreads();
    if (tid == 0) bsum[blockIdx.x] = ws_[0] + ws_[1] + ws_[2] + ws_[3];
}

__global__ void scan_bsum_k(int* __restrict__ bsum, int nb){
    __shared__ int tmp[1024];
    int tid = threadIdx.x;
    int v = (tid < nb) ? bsum[tid] : 0;
    tmp[tid] = v; __syncthreads();
    for (int off = 1; off < 1024; off <<= 1){
        int t = (tid >= off) ? tmp[tid-off] : 0;
        __syncthreads();
        tmp[tid] += t;
        __syncthreads();
    }
    if (tid < nb) bsum[tid] = tmp[tid] - v;   // exclusive
}

__global__ void block_scan_k(const int* __restrict__ cnt, const int* __restrict__ bexcl,
                             int* __restrict__ cursor, int* __restrict__ rowptr, int n){
    __shared__ int tmp[256];
    int tid = threadIdx.x;
    int i = blockIdx.x*256 + tid;
    int v = (i < n) ? cnt[i] : 0;
    tmp[tid] = v; __syncthreads();
    for (int off = 1; off < 256; off <<= 1){
        int t = (tid >= off) ? tmp[tid-off] : 0;
        __syncthreads();
        tmp[tid] += t;
        __syncthreads();
    }
    int excl = bexcl[blockIdx.x] + tmp[tid] - v;
    if (i < n){ cursor[i] = excl; rowptr[i+1] = excl + v; }
    if (i == 0) rowptr[0] = 0;
}

// csr_src only; edge weight computed in agg (halves the scattered-store traffic)
__global__ void place_edges_k(const int* __restrict__ ei, int* __restrict__ cursor,
                              int* __restrict__ csr_src, int E){
    int e = blockIdx.x*256 + threadIdx.x;
    if (e < E){
        int s = ei[e], d = ei[E + e];
        csr_src[atomicAdd(&cursor[d], 1)] = s;
    }
}

// ================= weight prep: fp32 [K][C] -> fp16 transposed [C][K] =================
struct WPA { const float* s; _Float16* d; int K; int C; };
struct WPA14 { WPA a[14]; };
__global__ void wprep_all_k(WPA14 args){
    WPA w = args.a[blockIdx.y];
    int idx = blockIdx.x*256 + threadIdx.x;
    if (idx < w.K*w.C){ int k = idx / w.C, c = idx % w.C; w.d[(size_t)c*w.K + k] = (_Float16)w.s[idx]; }
}

// ================= shared MFMA helpers (LDS-resident layer) =================
// A-frag: row=lane&15 (+16 per r), k=(lane>>4)*8 + kk*32 ; C/D: col=lane&15, row=(lane>>4)*4+reg
template<int K, int NC16, bool ZERO>
__device__ __forceinline__ void mfma_ldsmm(const _Float16* As, int lda,
        const _Float16* Ws, int ldw, f32x4 (&acc)[2][8], int ln, int q, int wid){
    if (ZERO){
        #pragma unroll
        for (int r = 0; r < 2; ++r)
            #pragma unroll
            for (int c = 0; c < 8; ++c) acc[r][c] = (f32x4){0.f,0.f,0.f,0.f};
    }
    #pragma unroll
    for (int kk = 0; kk < K/32; ++kk){
        int ko = kk*32 + q*8;
        f16x8 a0 = *(const f16x8*)&As[(size_t)(wid*32 + ln)*lda + ko];
        f16x8 a1 = *(const f16x8*)&As[(size_t)(wid*32 + 16 + ln)*lda + ko];
        #pragma unroll
        for (int c = 0; c < NC16; ++c){
            f16x8 b = *(const f16x8*)&Ws[(size_t)(c*16 + ln)*ldw + ko];
            acc[0][c] = __builtin_amdgcn_mfma_f32_16x16x32_f16(a0, b, acc[0][c], 0, 0, 0);
            acc[1][c] = __builtin_amdgcn_mfma_f32_16x16x32_f16(a1, b, acc[1][c], 0, 0, 0);
        }
    }
}

// ACT: 0 none, 1 sigmoid, 2 relu
template<int NC16, int ACT>
__device__ __forceinline__ void act_store_lds(_Float16* D, int ldd, f32x4 (&acc)[2][8],
        const float* bias, int ln, int q, int wid){
    #pragma unroll
    for (int r = 0; r < 2; ++r){
        int rowb = wid*32 + r*16 + q*4;
        #pragma unroll
        for (int c = 0; c < NC16; ++c){
            int col = c*16 + ln;
            float bv = bias ? bias[col] : 0.0f;
            #pragma unroll
            for (int i2 = 0; i2 < 4; ++i2){
                float v = acc[r][c][i2] + bv;
                if (ACT == 1) v = sigm(v);
                else if (ACT == 2) v = fmaxf(v, 0.0f);
                D[(size_t)(rowb + i2)*ldd + col] = (_Float16)v;
            }
        }
    }
}

__device__ __forceinline__ void stage_w(const _Float16* Wg, _Float16* Wl, int ldw,
                                        int C, int K, int tid){
    int kq = K/8, tot = C*kq;
    for (int i = tid; i < tot; i += 256){
        int r = i/kq, s = i%kq;
        *(f16x8*)&Wl[(size_t)r*ldw + s*8] = *(const f16x8*)&Wg[(size_t)r*K + s*8];
    }
}

// 128x128 fp16 weight: 2048 granules of 16B, 8 per thread
__device__ __forceinline__ void pf_load_w(const _Float16* Wg, f16x8 (&pf)[8], int tid){
    #pragma unroll
    for (int i = 0; i < 8; ++i) pf[i] = *(const f16x8*)&Wg[(size_t)(tid + i*256)*8];
}
__device__ __forceinline__ void pf_store_w(_Float16* Wl, f16x8 (&pf)[8], int tid){
    #pragma unroll
    for (int i = 0; i < 8; ++i){
        int g = tid + i*256; int r = g >> 4, s = g & 15;
        *(f16x8*)&Wl[(size_t)r*136 + s*8] = pf[i];
    }
}

// ================= fused input layer: g = (sigmoid(x@Win+bin)) @ Wgcn =================
__global__ __launch_bounds__(256,1) void fused_input_k(const float* __restrict__ x,
        const _Float16* __restrict__ WtIN, const float* __restrict__ b_in,
        const _Float16* __restrict__ WtGCN, _Float16* __restrict__ gOut, int nrows){
    __shared__ __align__(16) _Float16 Ax[128*40];
    __shared__ __align__(16) _Float16 Hl[128*136];
    __shared__ __align__(16) _Float16 Wi[128*40];
    __shared__ __align__(16) _Float16 Wg[128*136];
    int tid = threadIdx.x, lane = tid & 63, wid = tid >> 6;
    int ln = lane & 15, q = lane >> 4;
    int row0 = blockIdx.x * 128;
    for (int i = tid; i < 512; i += 256){
        int r = i >> 2, s = i & 3;
        f16x8 v = {};
        if (row0 + r < nrows){
            const float* xs = &x[(size_t)(row0+r)*DIN + s*8];
            float4 u0 = *(const float4*)xs, u1 = *(const float4*)(xs+4);
            v[0]=(_Float16)u0.x; v[1]=(_Float16)u0.y; v[2]=(_Float16)u0.z; v[3]=(_Float16)u0.w;
            v[4]=(_Float16)u1.x; v[5]=(_Float16)u1.y; v[6]=(_Float16)u1.z; v[7]=(_Float16)u1.w;
        }
        *(f16x8*)&Ax[r*40 + s*8] = v;
        *(f16x8*)&Wi[r*40 + s*8] = *(const f16x8*)&WtIN[(size_t)r*32 + s*8];
    }
    for (int i = tid; i < 2048; i += 256){
        int r = i >> 4, s = i & 15;
        *(f16x8*)&Wg[r*136 + s*8] = *(const f16x8*)&WtGCN[(size_t)r*128 + s*8];
    }
    __syncthreads();
    f32x4 acc[2][8];
    mfma_ldsmm<32,8,true>(Ax, 40, Wi, 40, acc, ln, q, wid);
    act_store_lds<8,1>(Hl, 136, acc, b_in, ln, q, wid);
    __syncthreads();
    mfma_ldsmm<128,8,true>(Hl, 136, Wg, 136, acc, ln, q, wid);
    #pragma unroll
    for (int r = 0; r < 2; ++r){
        int rowb = row0 + wid*32 + r*16 + q*4;
        #pragma unroll
        for (int c = 0; c < 8; ++c){
            int col = c*16 + ln;
            #pragma unroll
            for (int i2 = 0; i2 < 4; ++i2){
                int row = rowb + i2;
                if (row < nrows) gOut[(size_t)row*DL + col] = (_Float16)acc[r][c][i2];
            }
        }
    }
}

// ================= GCN aggregation (fp16 feats, fp32 accum, weight on the fly) ========
__global__ __launch_bounds__(256) void gcn_agg_h(const _Float16* __restrict__ g,
        _Float16* __restrict__ out, const int* __restrict__ rowptr,
        const int* __restrict__ csr_src, const float* __restrict__ dinv,
        const float* __restrict__ bgcn, int N){
    int t = threadIdx.x;
    int node = blockIdx.x*16 + (t >> 4);
    int f = (t & 15)*8;
    if (node >= N) return;
    float dv = dinv[node];
    float sn = dv*dv;
    f16x8 sv = *(const f16x8*)&g[(size_t)node*DL + f];
    float acc[8];
    #pragma unroll
    for (int j = 0; j < 8; ++j) acc[j] = (float)sv[j]*sn + bgcn[f+j];
    int e0 = rowptr[node], e1 = rowptr[node+1];
    for (int e = e0; e < e1; ++e){
        int s = csr_src[e];
        float w = dinv[s]*dv;
        f16x8 nv = *(const f16x8*)&g[(size_t)s*DL + f];
        #pragma unroll
        for (int j = 0; j < 8; ++j) acc[j] += (float)nv[j]*w;
    }
    f16x8 o;
    #pragma unroll
    for (int j = 0; j < 8; ++j) o[j] = (_Float16)acc[j];
    *(f16x8*)&out[(size_t)node*DL + f] = o;
}

// ================= fused hop: 5 enc layers + mu/std + reparam (+ gcn GEMM) ============
// Wt8 layout: m=0 gcn, 1..5 enc0..4, 6 mu, 7 std  (each [128][128] fp16 transposed)
template<int LAST>
__global__ __launch_bounds__(256,1) void fused_hop_k(const _Float16* __restrict__ g2,
        const _Float16* __restrict__ Wt8, const float* __restrict__ b_enc,
        const float* __restrict__ b_mu, const float* __restrict__ b_std,
        const float* __restrict__ eps_i, _Float16* __restrict__ gOut,
        float* __restrict__ muOut, float* __restrict__ stdOut,
        _Float16* __restrict__ hOut, int nrows){
    __shared__ __align__(16) _Float16 actA[128*136];
    __shared__ __align__(16) _Float16 actB[128*136];
    __shared__ __align__(16) _Float16 wb[2][128*136];
    int tid = threadIdx.x, lane = tid & 63, wid = tid >> 6;
    int ln = lane & 15, q = lane >> 4;
    int row0 = blockIdx.x * 128;
    // stage act tile + enc0 weights
    for (int i = tid; i < 2048; i += 256){
        int r = i >> 4, s = i & 15;
        f16x8 v = {};
        if (row0 + r < nrows) v = *(const f16x8*)&g2[(size_t)(row0+r)*DL + s*8];
        *(f16x8*)&actA[r*136 + s*8] = v;
        *(f16x8*)&wb[0][r*136 + s*8] = *(const f16x8*)&Wt8[(size_t)1*16384 + (size_t)r*128 + s*8];
    }
    __syncthreads();
    _Float16* src = actA; _Float16* dst = actB;
    int cur = 0;
    f32x4 acc[2][8], accS[2][8];
    f16x8 pf[8];
    #pragma unroll 1
    for (int j = 0; j < 5; ++j){
        const _Float16* nxtW = Wt8 + (size_t)((j < 4) ? (2+j) : 6)*16384;  // enc j+1 or mu
        pf_load_w(nxtW, pf, tid);
        mfma_ldsmm<128,8,true>(src, 136, wb[cur], 136, acc, ln, q, wid);
        pf_store_w(wb[cur^1], pf, tid);
        act_store_lds<8,1>(dst, 136, acc, b_enc + j*DL, ln, q, wid);
        cur ^= 1;
        { _Float16* t = src; src = dst; dst = t; }
        __syncthreads();
    }
    // mu (wb[cur] holds Wmu); prefetch Wstd
    pf_load_w(Wt8 + (size_t)7*16384, pf, tid);
    mfma_ldsmm<128,8,true>(src, 136, wb[cur], 136, acc, ln, q, wid);
    pf_store_w(wb[cur^1], pf, tid);
    cur ^= 1;
    __syncthreads();
    // std; prefetch Wgcn if needed
    if (!LAST) pf_load_w(Wt8, pf, tid);
    mfma_ldsmm<128,8,true>(src, 136, wb[cur], 136, accS, ln, q, wid);
    if (!LAST) pf_store_w(wb[cur^1], pf, tid);
    cur ^= 1;
    // epilogue: mu, std=softplus(.-5), h = mu + std*eps
    #pragma unroll
    for (int r = 0; r < 2; ++r){
        int rowb = wid*32 + r*16 + q*4;
        #pragma unroll
        for (int c = 0; c < 8; ++c){
            int col = c*16 + ln;
            float bm = b_mu[col], bs = b_std[col];
            #pragma unroll
            for (int i2 = 0; i2 < 4; ++i2){
                int row = rowb + i2;
                int grow = row0 + row;
                float mv = acc[r][c][i2] + bm;
                float sv = softplus_(accS[r][c][i2] + bs - 5.0f);
                float ev = (grow < nrows) ? eps_i[(size_t)grow*DL + col] : 0.0f;
                float hv = mv + sv*ev;
                if (LAST){
                    if (grow < nrows){
                        muOut[(size_t)grow*DL + col] = mv;
                        stdOut[(size_t)grow*DL + col] = sv;
                        hOut[(size_t)grow*DL + col] = (_Float16)hv;
                    }
                } else {
                    dst[(size_t)row*136 + col] = (_Float16)hv;
                }
            }
        }
    }
    if (!LAST){
        __syncthreads();   // h complete in dst, Wgcn in wb[cur]
        mfma_ldsmm<128,8,true>(dst, 136, wb[cur], 136, acc, ln, q, wid);
        #pragma unroll
        for (int r = 0; r < 2; ++r){
            int rowb = row0 + wid*32 + r*16 + q*4;
            #pragma unroll
            for (int c = 0; c < 8; ++c){
                int col = c*16 + ln;
                #pragma unroll
                for (int i2 = 0; i2 < 4; ++i2){
                    int row = rowb + i2;
                    if (row < nrows) gOut[(size_t)row*DL + col] = (_Float16)acc[r][c][i2];
                }
            }
        }
    }
}

// ================= fused decoder: 128->256->128->64->32->16->10 + mean-pool ===========
__global__ __launch_bounds__(256,1) void decoder_k(const _Float16* __restrict__ h,
        const _Float16* __restrict__ WtD0, const _Float16* __restrict__ WtD1,
        const _Float16* __restrict__ WtD2, const _Float16* __restrict__ WtD3,
        const _Float16* __restrict__ WtD4,
        const float* __restrict__ bd0, const float* __restrict__ bd1,
        const float* __restrict__ bd2, const float* __restrict__ bd3,
        const float* __restrict__ bd4, const float* __restrict__ Wo,
        const float* __restrict__ bo, const int* __restrict__ batch,
        float* __restrict__ sums, float* __restrict__ gcnt, int nrows){
    __shared__ __align__(16) _Float16 A[128*136];
    __shared__ __align__(16) _Float16 B[128*264];
    __shared__ __align__(16) _Float16 W[128*136];
    __shared__ float WoL[16*DOUT];
    __shared__ float boL[DOUT];
    int tid = threadIdx.x, lane = tid & 63, wid = tid >> 6;
    int ln = lane & 15, q = lane >> 4;
    int row0 = blockIdx.x * 128;
    for (int i = tid; i < 2048; i += 256){
        int r = i >> 4, s = i & 15;
        f16x8 v = {};
        if (row0 + r < nrows) v = *(const f16x8*)&h[(size_t)(row0+r)*DL + s*8];
        *(f16x8*)&A[r*136 + s*8] = v;
    }
    if (tid < 16*DOUT) WoL[tid] = Wo[tid];
    if (tid < DOUT) boL[tid] = bo[tid];
    f32x4 acc[2][8];
    // d0: 128 -> 256 (two col-halves)
    for (int ch = 0; ch < 2; ++ch){
        stage_w(WtD0 + (size_t)ch*128*128, W, 136, 128, 128, tid);
        __syncthreads();
        mfma_ldsmm<128,8,true>(A, 136, W, 136, acc, ln, q, wid);
        act_store_lds<8,2>(B + ch*128, 264, acc, bd0 + ch*128, ln, q, wid);
        __syncthreads();
    }
    // d1: 256 -> 128 (two K-halves, accumulate)
    for (int kh = 0; kh < 2; ++kh){
        for (int i = tid; i < 2048; i += 256){
            int r = i >> 4, s = i & 15;
            *(f16x8*)&W[r*136 + s*8] = *(const f16x8*)&WtD1[(size_t)r*256 + kh*128 + s*8];
        }
        __syncthreads();
        if (kh == 0) mfma_ldsmm<128,8,true >(B,       264, W, 136, acc, ln, q, wid);
        else         mfma_ldsmm<128,8,false>(B + 128, 264, W, 136, acc, ln, q, wid);
        __syncthreads();
    }
    act_store_lds<8,2>(A, 136, acc, bd1, ln, q, wid);
    __syncthreads();
    // d2: 128 -> 64
    stage_w(WtD2, W, 136, 64, 128, tid);
    __syncthreads();
    mfma_ldsmm<128,4,true>(A, 136, W, 136, acc, ln, q, wid);
    act_store_lds<4,2>(B, 264, acc, bd2, ln, q, wid);
    __syncthreads();
    // d3: 64 -> 32
    stage_w(WtD3, W, 136, 32, 64, tid);
    __syncthreads();
    mfma_ldsmm<64,2,true>(B, 264, W, 136, acc, ln, q, wid);
    act_store_lds<2,2>(A, 136, acc, bd3, ln, q, wid);
    __syncthreads();
    // d4: 32 -> 16
    stage_w(WtD4, W, 136, 16, 32, tid);
    __syncthreads();
    mfma_ldsmm<32,1,true>(A, 136, W, 136, acc, ln, q, wid);
    act_store_lds<1,2>(B, 264, acc, bd4, ln, q, wid);
    __syncthreads();
    // final 16 -> 10 sigmoid + mean-pool accumulation
    int node = row0 + tid;
    bool valid = (tid < 128) && (node < nrows);
    float yp[DOUT];
    int b = -1;
    if (valid){
        float dd[16];
        #pragma unroll
        for (int k = 0; k < 16; ++k) dd[k] = (float)B[(size_t)tid*264 + k];
        #pragma unroll
        for (int o = 0; o < DOUT; ++o){
            float a2 = boL[o];
            #pragma unroll
            for (int k = 0; k < 16; ++k) a2 += dd[k]*WoL[k*DOUT + o];
            yp[o] = sigm(a2);
        }
        b = batch[node];
    }
    int b0 = __builtin_amdgcn_readfirstlane(b);
    unsigned long long m = __ballot(b == b0);
    if (m == ~0ull && b0 >= 0){
        #pragma unroll
        for (int o = 0; o < DOUT; ++o){
            float v = yp[o];
            for (int off = 32; off > 0; off >>= 1) v += __shfl_xor(v, off);
            if ((tid & 63) == 0) atomicAdd(&sums[b0*DOUT + o], v);
        }
        if ((tid & 63) == 0) atomicAdd(&gcnt[b0], 64.0f);
    } else if (valid){
        #pragma unroll
        for (int o = 0; o < DOUT; ++o) atomicAdd(&sums[b*DOUT + o], yp[o]);
        atomicAdd(&gcnt[b], 1.0f);
    }
}

__global__ void divide_k(float* __restrict__ out, const float* __restrict__ gcnt, int n){
    int i = blockIdx.x*256 + threadIdx.x;
    if (i < n) out[i] = out[i] / fmaxf(gcnt[i/DOUT], 1.0f);
}

__global__ void copy_k(const float* __restrict__ src, float* __restrict__ dst, int n){
    int i = blockIdx.x*256 + threadIdx.x;
    if (i < n) dst[i] = src[i];
}

extern "C" void kernel_launch(void* const* d_in, const int* in_sizes, int n_in,
                              void* d_out, int out_size, void* d_ws, size_t ws_size,
                              hipStream_t stream) {
    const float* x     = (const float*)d_in[0];
    const int*   ei    = (const int*)d_in[1];
    const int*   batch = (const int*)d_in[2];
    const float* y     = (const float*)d_in[3];
    const float* eps   = (const float*)d_in[4];
    const float* W_in  = (const float*)d_in[5];
    const float* b_in  = (const float*)d_in[6];
    const float* W_gcn = (const float*)d_in[7];
    const float* b_gcn = (const float*)d_in[8];
    const float* W_enc = (const float*)d_in[9];
    const float* b_enc = (const float*)d_in[10];
    const float* W_mu  = (const float*)d_in[11];
    const float* b_mu  = (const float*)d_in[12];
    const float* W_std = (const float*)d_in[13];
    const float* b_std = (const float*)d_in[14];
    const float* Wd0 = (const float*)d_in[15]; const float* bd0 = (const float*)d_in[16];
    const float* Wd1 = (const float*)d_in[17]; const float* bd1 = (const float*)d_in[18];
    const float* Wd2 = (const float*)d_in[19]; const float* bd2 = (const float*)d_in[20];
    const float* Wd3 = (const float*)d_in[21]; const float* bd3 = (const float*)d_in[22];
    const float* Wd4 = (const float*)d_in[23]; const float* bd4 = (const float*)d_in[24];
    const float* Wo  = (const float*)d_in[25]; const float* bo  = (const float*)d_in[26];

    const int N = in_sizes[2];
    const int E = in_sizes[1]/2;
    const int G = in_sizes[3]/DOUT;
    const int KHOP = in_sizes[4] / (N*DL);   // = 3
    const size_t NN = (size_t)N*DL;

    char* p = (char*)d_ws;
    auto take = [&p](size_t bytes) -> char* {
        char* r = p; p += (bytes + 255) & ~(size_t)255; return r;
    };
    _Float16* hG  = (_Float16*)take(NN*2);
    _Float16* hG2 = (_Float16*)take(NN*2);
    _Float16* hH  = (_Float16*)take(NN*2);
    float* dinv  = (float*)take((size_t)N*4);
    float* gcnt  = (float*)take((size_t)G*4);
    int* cnt     = (int*)take((size_t)N*4);
    int* rowptr  = (int*)take((size_t)(N+1)*4);
    int* cursor  = (int*)take((size_t)N*4);
    int* csr_src = (int*)take((size_t)E*4);
    int* bsum    = (int*)take(1024*4);
    _Float16* Wt8  = (_Float16*)take((size_t)8*DL*DL*2);  // gcn, enc0..4, mu, std
    _Float16* WtIN = (_Float16*)take((size_t)DL*DIN*2);
    _Float16* WtD0 = (_Float16*)take((size_t)256*128*2);
    _Float16* WtD1 = (_Float16*)take((size_t)128*256*2);
    _Float16* WtD2 = (_Float16*)take((size_t)64*128*2);
    _Float16* WtD3 = (_Float16*)take((size_t)32*64*2);
    _Float16* WtD4 = (_Float16*)take((size_t)16*32*2);

    float* out_ypred = (float*)d_out;                    // [G,10]
    float* out_mu    = out_ypred + (size_t)G*DOUT;       // [N,128]
    float* out_std   = out_mu + NN;                      // [N,128]
    float* out_y     = out_std + NN;                     // [G,10]

    hipMemsetAsync(cnt, 0, sizeof(int)*N, stream);
    hipMemsetAsync(out_ypred, 0, sizeof(float)*G*DOUT, stream);
    hipMemsetAsync(gcnt, 0, sizeof(float)*G, stream);

    int gE = (E + 255)/256, gN = (N + 255)/256;
    int nb = gN;

    count_edges_k<<<gE, 256, 0, stream>>>(ei, cnt, E);
    dinv_k<<<gN, 256, 0, stream>>>(cnt, dinv, N);
    block_sum_k<<<nb, 256, 0, stream>>>(cnt, bsum, N);
    scan_bsum_k<<<1, 1024, 0, stream>>>(bsum, nb);
    block_scan_k<<<nb, 256, 0, stream>>>(cnt, bsum, cursor, rowptr, N);
    place_edges_k<<<gE, 256, 0, stream>>>(ei, cursor, csr_src, E);

    // weight prep (single batched kernel)
    WPA14 wa;
    wa.a[0]  = { W_in,  WtIN, DIN, DL };
    wa.a[1]  = { W_gcn, Wt8,  DL, DL };
    for (int j = 0; j < 5; ++j) wa.a[2+j] = { W_enc + (size_t)j*DL*DL, Wt8 + (size_t)(1+j)*DL*DL, DL, DL };
    wa.a[7]  = { W_mu,  Wt8 + (size_t)6*DL*DL, DL, DL };
    wa.a[8]  = { W_std, Wt8 + (size_t)7*DL*DL, DL, DL };
    wa.a[9]  = { Wd0, WtD0, 128, 256 };
    wa.a[10] = { Wd1, WtD1, 256, 128 };
    wa.a[11] = { Wd2, WtD2, 128, 64 };
    wa.a[12] = { Wd3, WtD3, 64, 32 };
    wa.a[13] = { Wd4, WtD4, 32, 16 };
    wprep_all_k<<<dim3(128, 14), 256, 0, stream>>>(wa);

    int ntile = (N + 127)/128;
    fused_input_k<<<ntile, 256, 0, stream>>>(x, WtIN, b_in, Wt8, hG, N);

    for (int i = 0; i < KHOP; ++i){
        gcn_agg_h<<<(N+15)/16, 256, 0, stream>>>(hG, hG2, rowptr, csr_src, dinv, b_gcn, N);
        const float* eps_i = eps + (size_t)i*NN;
        if (i == KHOP-1)
            fused_hop_k<1><<<ntile, 256, 0, stream>>>(hG2, Wt8, b_enc, b_mu, b_std, eps_i,
                                                      nullptr, out_mu, out_std, hH, N);
        else
            fused_hop_k<0><<<ntile, 256, 0, stream>>>(hG2, Wt8, b_enc, b_mu, b_std, eps_i,
                                                      hG, nullptr, nullptr, nullptr, N);
    }

    decoder_k<<<ntile, 256, 0, stream>>>(hH, WtD0, WtD1, WtD2, WtD3, WtD4,
                                         bd0, bd1, bd2, bd3, bd4, Wo, bo,
                                         batch, out_ypred, gcnt, N);
    divide_k<<<(G*DOUT+255)/256, 256, 0, stream>>>(out_ypred, gcnt, G*DOUT);
    copy_k<<<(G*DOUT+255)/256, 256, 0, stream>>>(y, out_y, G*DOUT);
}